// Round 5
// baseline (139.431 us; speedup 1.0000x reference)
//
#include <hip/hip_runtime.h>

// Problem dims (fixed by reference setup_inputs)
#define BDIM 256
#define IDIM 1024
#define ODIM 1024

#define TILE_O 64   // outputs per block (one per lane)
#define TILE_B 4    // batches per block (one per wave / ty)
#define CH 64       // i-chunk per barrier
#define ISPLIT 2    // i-dim halves -> 2x wave count
#define IHALF (IDIM / ISPLIT)      // 512 i per block
#define NCH (IHALF / CH)           // 8 chunks

typedef float v2f __attribute__((ext_vector_type(2)));

#if __has_builtin(__builtin_amdgcn_exp2f)
#define FAST_EXP2(v) __builtin_amdgcn_exp2f(v)
#else
#define FAST_EXP2(v) exp2f(v)
#endif

__global__ __launch_bounds__(256, 8)
void stl_partial_kernel(const float* __restrict__ x,
                        const float* __restrict__ w,
                        float2* __restrict__ part) {
  __shared__ float ws[CH][TILE_O];   // 16 KB: w chunk
  __shared__ float xs[TILE_B][CH];   // 1 KB: x chunk, prescaled by log2e

  const int tx = threadIdx.x;            // 0..63 -> output column (lane)
  const int ty = threadIdx.y;            // 0..3  -> batch row (one wave each)
  const int tid = ty * 64 + tx;          // 0..255
  const int o0 = blockIdx.x * TILE_O;
  const int b0 = blockIdx.y * TILE_B;
  const int half = blockIdx.z;
  const int ibase = half * IHALF;

  const float LOG2E = 1.4426950408889634f;  // folds 1/TEMPERATURE too
  const float* xrow = x + (size_t)(b0 + ty) * IDIM + ibase;

  // w staging addressing: thread tid covers rows f>>4, float4-col f&15
  const int wrow[4] = {(tid) >> 4, (tid + 256) >> 4, (tid + 512) >> 4, (tid + 768) >> 4};
  const int wcol = tid & 15;

  // ---- Prologue: prefetch chunk 0 into registers ----
  float4 wreg[4];
  float4 xreg;
#pragma unroll
  for (int k = 0; k < 4; ++k)
    wreg[k] = *(const float4*)(w + (size_t)(ibase + wrow[k]) * ODIM + o0 + wcol * 4);
  if (tx < CH / 4) xreg = *(const float4*)(xrow + tx * 4);

  // Packed accumulators over i-parity: .x = even i, .y = odd i.
  v2f num = {0.0f, 0.0f};
  v2f den = {0.0f, 0.0f};

  for (int c = 0; c < NCH; ++c) {
    __syncthreads();   // previous chunk's LDS reads complete
    // ---- Commit staged registers to LDS ----
    if (tx < CH / 4) {
      float4 v = xreg;
      v.x *= LOG2E; v.y *= LOG2E; v.z *= LOG2E; v.w *= LOG2E;
      *(float4*)(&xs[ty][tx * 4]) = v;
    }
#pragma unroll
    for (int k = 0; k < 4; ++k)
      *(float4*)(&ws[wrow[k]][wcol * 4]) = wreg[k];

    // ---- Prefetch next chunk into registers (latency hidden by compute) ----
    if (c + 1 < NCH) {
      const int i1 = ibase + (c + 1) * CH;
#pragma unroll
      for (int k = 0; k < 4; ++k)
        wreg[k] = *(const float4*)(w + (size_t)(i1 + wrow[k]) * ODIM + o0 + wcol * 4);
      if (tx < CH / 4) xreg = *(const float4*)(xrow + (c + 1) * CH + tx * 4);
    }
    __syncthreads();   // LDS visible

    // ---- Inner reduction: 8 i per group ----
#pragma unroll 4
    for (int j = 0; j < CH; j += 8) {
      float4 xq0 = *(const float4*)(&xs[ty][j]);       // broadcast ds_read_b128
      float4 xq1 = *(const float4*)(&xs[ty][j + 4]);   // broadcast ds_read_b128
      float wv[8];
#pragma unroll
      for (int u = 0; u < 8; ++u) wv[u] = ws[j + u][tx];  // pairs -> ds_read2_b32
      v2f p0 = {xq0.x * wv[0], xq0.y * wv[1]};   // p = log2e * z
      v2f p1 = {xq0.z * wv[2], xq0.w * wv[3]};
      v2f p2 = {xq1.x * wv[4], xq1.y * wv[5]};
      v2f p3 = {xq1.z * wv[6], xq1.w * wv[7]};
      v2f t0, t1, t2, t3;
      t0.x = FAST_EXP2(__builtin_fabsf(p0.x));
      t0.y = FAST_EXP2(__builtin_fabsf(p0.y));
      t1.x = FAST_EXP2(__builtin_fabsf(p1.x));
      t1.y = FAST_EXP2(__builtin_fabsf(p1.y));
      t2.x = FAST_EXP2(__builtin_fabsf(p2.x));
      t2.y = FAST_EXP2(__builtin_fabsf(p2.y));
      t3.x = FAST_EXP2(__builtin_fabsf(p3.x));
      t3.y = FAST_EXP2(__builtin_fabsf(p3.y));
      num += p0 * t0; den += t0;   // v_pk_fma_f32 / v_pk_add_f32
      num += p1 * t1; den += t1;
      num += p2 * t2; den += t2;
      num += p3 * t3; den += t3;
    }
  }

  // ---- Write partial (num, den) ----
  const int o = o0 + tx;
  part[(size_t)half * (BDIM * ODIM) + (size_t)(b0 + ty) * ODIM + o] =
      make_float2(num.x + num.y, den.x + den.y);
}

__global__ __launch_bounds__(256)
void stl_combine_kernel(const float2* __restrict__ part,
                        const float* __restrict__ bias,
                        float* __restrict__ out) {
  const int idx = blockIdx.x * 256 + threadIdx.x;   // 0..262143
  const int o = idx & (ODIM - 1);
  const float2 a = part[idx];
  const float2 b = part[BDIM * ODIM + idx];
  const float LN2 = 0.6931471805599453f;
  const float scale = (float)IDIM * LN2;
  out[idx] = scale * (a.x + b.x) / (a.y + b.y) + bias[o];
}

extern "C" void kernel_launch(void* const* d_in, const int* in_sizes, int n_in,
                              void* d_out, int out_size, void* d_ws, size_t ws_size,
                              hipStream_t stream) {
  const float* x = (const float*)d_in[0];    // [256,1024] f32
  const float* w = (const float*)d_in[1];    // [1024,1024] f32
  const float* b = (const float*)d_in[2];    // [1024] f32
  float* out = (float*)d_out;                // [256,1024] f32
  float2* part = (float2*)d_ws;              // [2][256][1024] float2 = 4 MB

  dim3 grid(ODIM / TILE_O, BDIM / TILE_B, ISPLIT);  // (16, 64, 2) = 2048 blocks
  dim3 block(64, 4);
  stl_partial_kernel<<<grid, block, 0, stream>>>(x, w, part);

  stl_combine_kernel<<<(BDIM * ODIM) / 256, 256, 0, stream>>>(part, b, out);
}

// Round 6
// 96.338 us; speedup vs baseline: 1.4473x; 1.4473x over previous
//
#include <hip/hip_runtime.h>

// Problem dims (fixed by reference setup_inputs)
#define BDIM 256
#define IDIM 1024
#define ODIM 1024

#define TILE_O 64   // outputs per block (one per lane)
#define TILE_B 2    // batches per block (packed as v2f per thread)
#define NQ 4        // i-quarters (one per wave); combine via LDS at end
#define QLEN (IDIM / NQ)   // 256 i per wave

typedef float v2f __attribute__((ext_vector_type(2)));

#if __has_builtin(__builtin_amdgcn_exp2f)
#define FAST_EXP2(v) __builtin_amdgcn_exp2f(v)
#else
#define FAST_EXP2(v) exp2f(v)
#endif

__global__ __launch_bounds__(256, 8)
void stl_kernel(const float* __restrict__ x,
                const float* __restrict__ w,
                const float* __restrict__ bias,
                float* __restrict__ out) {
  __shared__ float xs[TILE_B][IDIM];   // 8 KB: both x rows, prescaled by log2e
  __shared__ float ps[NQ][TILE_O][4];  // 4 KB: per-wave partials {num.x,num.y,den.x,den.y}

  const int tx = threadIdx.x;          // 0..63 -> output column (lane)
  const int ty = threadIdx.y;          // 0..3  -> i-quarter (one wave each)
  const int tid = ty * 64 + tx;
  const int o0 = blockIdx.x * TILE_O;
  const int b0 = blockIdx.y * TILE_B;

  const float LOG2E = 1.4426950408889634f;  // folds 1/TEMPERATURE too

  // ---- Stage both x rows once (coalesced, prescaled). Only barrier #1. ----
#pragma unroll
  for (int k = 0; k < 2; ++k) {
    int f = tid + k * 256;             // 0..511 float4s
    int row = f >> 8;                  // 256 float4 per row
    int col = f & 255;
    float4 v = ((const float4*)(x + (size_t)(b0 + row) * IDIM))[col];
    v.x *= LOG2E; v.y *= LOG2E; v.z *= LOG2E; v.w *= LOG2E;
    ((float4*)(&xs[row][0]))[col] = v;
  }
  __syncthreads();

  // ---- Barrier-free main loop: w from global (L2-resident, 4 MB), x from LDS ----
  const int qbase = ty * QLEN;
  const float* wp = w + (size_t)qbase * ODIM + o0 + tx;

  v2f num = {0.0f, 0.0f};   // .x = batch b0, .y = batch b0+1
  v2f den = {0.0f, 0.0f};

#pragma unroll 2
  for (int j = 0; j < QLEN; j += 8) {
    float wv[8];
#pragma unroll
    for (int u = 0; u < 8; ++u) wv[u] = wp[(size_t)(j + u) * ODIM];  // coalesced 256B/wave
    float4 xa0 = *(const float4*)(&xs[0][qbase + j]);       // broadcast b128
    float4 xa1 = *(const float4*)(&xs[0][qbase + j + 4]);
    float4 xb0 = *(const float4*)(&xs[1][qbase + j]);
    float4 xb1 = *(const float4*)(&xs[1][qbase + j + 4]);
    const float xa[8] = {xa0.x, xa0.y, xa0.z, xa0.w, xa1.x, xa1.y, xa1.z, xa1.w};
    const float xb[8] = {xb0.x, xb0.y, xb0.z, xb0.w, xb1.x, xb1.y, xb1.z, xb1.w};
#pragma unroll
    for (int u = 0; u < 8; ++u) {
      v2f p = {xa[u] * wv[u], xb[u] * wv[u]};   // p = log2e * z
      v2f t;
      t.x = FAST_EXP2(__builtin_fabsf(p.x));    // single v_exp_f32, abs folded
      t.y = FAST_EXP2(__builtin_fabsf(p.y));
      num += p * t;                              // v_pk_fma_f32
      den += t;                                  // v_pk_add_f32
    }
  }

  // ---- Cross-wave combine (barrier #2) ----
  *(float4*)(&ps[ty][tx][0]) = make_float4(num.x, num.y, den.x, den.y);
  __syncthreads();

  if (ty == 0) {
    float4 a = *(const float4*)(&ps[0][tx][0]);
    float4 b = *(const float4*)(&ps[1][tx][0]);
    float4 c = *(const float4*)(&ps[2][tx][0]);
    float4 d = *(const float4*)(&ps[3][tx][0]);
    const float nx = a.x + b.x + c.x + d.x;
    const float ny = a.y + b.y + c.y + d.y;
    const float dx = a.z + b.z + c.z + d.z;
    const float dy = a.w + b.w + c.w + d.w;
    const float LN2 = 0.6931471805599453f;
    const float scale = (float)IDIM * LN2;      // undo log2e, apply n
    const int o = o0 + tx;
    const float bo = bias[o];
    out[(size_t)b0 * ODIM + o] = scale * nx / dx + bo;
    out[(size_t)(b0 + 1) * ODIM + o] = scale * ny / dy + bo;
  }
}

extern "C" void kernel_launch(void* const* d_in, const int* in_sizes, int n_in,
                              void* d_out, int out_size, void* d_ws, size_t ws_size,
                              hipStream_t stream) {
  const float* x = (const float*)d_in[0];    // [256,1024] f32
  const float* w = (const float*)d_in[1];    // [1024,1024] f32
  const float* b = (const float*)d_in[2];    // [1024] f32
  float* out = (float*)d_out;                // [256,1024] f32

  dim3 grid(ODIM / TILE_O, BDIM / TILE_B);   // (16, 128) = 2048 blocks = 8/CU
  dim3 block(64, 4);
  stl_kernel<<<grid, block, 0, stream>>>(x, w, b, out);
}

// Round 7
// 95.144 us; speedup vs baseline: 1.4655x; 1.0126x over previous
//
#include <hip/hip_runtime.h>

// Problem dims (fixed by reference setup_inputs)
#define BDIM 256
#define IDIM 1024
#define ODIM 1024

#define TILE_O 64   // outputs per block (one per lane)
#define TILE_B 4    // batch rows per block (all 4 in each thread, 2x v2f packed)
#define NW 8        // waves per block, each owns an i-eighth
#define QLEN (IDIM / NW)   // 128 i per wave

typedef float v2f __attribute__((ext_vector_type(2)));

#if __has_builtin(__builtin_amdgcn_exp2f)
#define FAST_EXP2(v) __builtin_amdgcn_exp2f(v)
#else
#define FAST_EXP2(v) exp2f(v)
#endif

__global__ __launch_bounds__(512, 8)
void stl_kernel(const float* __restrict__ x,
                const float* __restrict__ w,
                const float* __restrict__ bias,
                float* __restrict__ out) {
  __shared__ float xs[TILE_B][IDIM];   // 16 KB: 4 x rows, prescaled by log2e
  __shared__ float ps[NW][TILE_O][8];  // 16 KB: per-wave partials (4 num + 4 den)

  const int tx = threadIdx.x;          // 0..63 -> output column (lane)
  const int ty = threadIdx.y;          // 0..7  -> i-eighth (one wave each)
  const int tid = ty * 64 + tx;
  const int o0 = blockIdx.x * TILE_O;
  const int b0 = blockIdx.y * TILE_B;

  const float LOG2E = 1.4426950408889634f;  // folds 1/TEMPERATURE too

  // ---- Stage 4 x rows once (coalesced, prescaled). Barrier #1. ----
#pragma unroll
  for (int k = 0; k < 2; ++k) {
    int f = tid + k * 512;             // 0..1023 float4s
    int row = f >> 8;                  // 256 float4 per row
    int col = f & 255;
    float4 v = ((const float4*)(x + (size_t)(b0 + row) * IDIM))[col];
    v.x *= LOG2E; v.y *= LOG2E; v.z *= LOG2E; v.w *= LOG2E;
    ((float4*)(&xs[row][0]))[col] = v;
  }
  __syncthreads();

  // ---- Barrier-free main loop: w from global (L2-resident), x from LDS ----
  const int qbase = ty * QLEN;
  const float* wp = w + (size_t)qbase * ODIM + o0 + tx;

  v2f num01 = {0.0f, 0.0f}, num23 = {0.0f, 0.0f};  // batches (b0,b0+1), (b0+2,b0+3)
  v2f den01 = {0.0f, 0.0f}, den23 = {0.0f, 0.0f};

#pragma unroll 2
  for (int j = 0; j < QLEN; j += 4) {
    float wv[4];
#pragma unroll
    for (int u = 0; u < 4; ++u) wv[u] = wp[(size_t)(j + u) * ODIM];  // 1 load serves 4 elems
    float4 xq0 = *(const float4*)(&xs[0][qbase + j]);   // broadcast b128 reads
    float4 xq1 = *(const float4*)(&xs[1][qbase + j]);
    float4 xq2 = *(const float4*)(&xs[2][qbase + j]);
    float4 xq3 = *(const float4*)(&xs[3][qbase + j]);
    const float x0[4] = {xq0.x, xq0.y, xq0.z, xq0.w};
    const float x1[4] = {xq1.x, xq1.y, xq1.z, xq1.w};
    const float x2[4] = {xq2.x, xq2.y, xq2.z, xq2.w};
    const float x3[4] = {xq3.x, xq3.y, xq3.z, xq3.w};
#pragma unroll
    for (int u = 0; u < 4; ++u) {
      v2f p01 = {x0[u] * wv[u], x1[u] * wv[u]};   // p = log2e * z
      v2f p23 = {x2[u] * wv[u], x3[u] * wv[u]};
      v2f t01, t23;
      t01.x = FAST_EXP2(__builtin_fabsf(p01.x));  // single v_exp_f32, abs folded
      t01.y = FAST_EXP2(__builtin_fabsf(p01.y));
      t23.x = FAST_EXP2(__builtin_fabsf(p23.x));
      t23.y = FAST_EXP2(__builtin_fabsf(p23.y));
      num01 += p01 * t01; den01 += t01;           // v_pk_fma / v_pk_add
      num23 += p23 * t23; den23 += t23;
    }
  }

  // ---- Cross-wave combine (barrier #2) ----
  *(float4*)(&ps[ty][tx][0]) = make_float4(num01.x, num01.y, num23.x, num23.y);
  *(float4*)(&ps[ty][tx][4]) = make_float4(den01.x, den01.y, den23.x, den23.y);
  __syncthreads();

  if (ty == 0) {
    float n[4] = {0, 0, 0, 0}, d[4] = {0, 0, 0, 0};
#pragma unroll
    for (int q = 0; q < NW; ++q) {
      float4 a = *(const float4*)(&ps[q][tx][0]);
      float4 b = *(const float4*)(&ps[q][tx][4]);
      n[0] += a.x; n[1] += a.y; n[2] += a.z; n[3] += a.w;
      d[0] += b.x; d[1] += b.y; d[2] += b.z; d[3] += b.w;
    }
    const float LN2 = 0.6931471805599453f;
    const float scale = (float)IDIM * LN2;        // undo log2e, apply n
    const int o = o0 + tx;
    const float bo = bias[o];
#pragma unroll
    for (int r = 0; r < 4; ++r)
      out[(size_t)(b0 + r) * ODIM + o] = scale * n[r] / d[r] + bo;
  }
}

extern "C" void kernel_launch(void* const* d_in, const int* in_sizes, int n_in,
                              void* d_out, int out_size, void* d_ws, size_t ws_size,
                              hipStream_t stream) {
  const float* x = (const float*)d_in[0];    // [256,1024] f32
  const float* w = (const float*)d_in[1];    // [1024,1024] f32
  const float* b = (const float*)d_in[2];    // [1024] f32
  float* out = (float*)d_out;                // [256,1024] f32

  dim3 grid(ODIM / TILE_O, BDIM / TILE_B);   // (16, 64) = 1024 blocks = 4/CU
  dim3 block(64, NW);                        // 512 threads = 8 waves
  stl_kernel<<<grid, block, 0, stream>>>(x, w, b, out);
}